// Round 1
// baseline (1064.257 us; speedup 1.0000x reference)
//
#include <hip/hip_runtime.h>

typedef unsigned short u16;
typedef __attribute__((ext_vector_type(8))) short short8;
typedef __attribute__((ext_vector_type(4))) float floatx4;

#define SOS 3
#define EOS 4
#define NEGV -10000.0f

__device__ __forceinline__ float bf2f(u16 u) {
  union { unsigned int i; float f; } v; v.i = ((unsigned int)u) << 16; return v.f;
}
__device__ __forceinline__ u16 f2bf(float f) {
  union { float f; unsigned int i; } v; v.f = f;
  unsigned int r = (v.i + 0x7FFFu + ((v.i >> 16) & 1u)) >> 16;
  return (u16)r;
}
__device__ __forceinline__ float sigm(float x) { return 1.f / (1.f + __expf(-x)); }
__device__ __forceinline__ float tanhfast(float x) { return 2.f / (1.f + __expf(-2.f * x)) - 1.f; }

// ---------------- gather: A[65536][320] bf16 = embed[x[m]][k], zero-pad k>=300
__global__ __launch_bounds__(256) void gather_kernel(const float* __restrict__ embed,
                                                     const int* __restrict__ x,
                                                     u16* __restrict__ A) {
  int idx = blockIdx.x * 256 + threadIdx.x;   // 65536*40 chunks of 8
  int row = idx / 40;
  int c8 = idx - row * 40;
  int col0 = c8 * 8;
  const float* src = embed + (size_t)x[row] * 300 + col0;
  short8 o;
  if (col0 + 8 <= 300) {
    float4 f0 = *(const float4*)(src);
    float4 f1 = *(const float4*)(src + 4);
    o[0] = (short)f2bf(f0.x); o[1] = (short)f2bf(f0.y);
    o[2] = (short)f2bf(f0.z); o[3] = (short)f2bf(f0.w);
    o[4] = (short)f2bf(f1.x); o[5] = (short)f2bf(f1.y);
    o[6] = (short)f2bf(f1.z); o[7] = (short)f2bf(f1.w);
  } else {
    #pragma unroll
    for (int e = 0; e < 8; ++e)
      o[e] = (col0 + e < 300) ? (short)f2bf(src[e]) : (short)0;
  }
  *(short8*)&A[(size_t)row * 320 + col0] = o;
}

// ---------------- pack W: Wp[1024][320] bf16 = [Wih_f; Wih_b], zero-pad
__global__ __launch_bounds__(256) void wpack_kernel(const float* __restrict__ Wf,
                                                    const float* __restrict__ Wb,
                                                    u16* __restrict__ Wp) {
  int idx = blockIdx.x * 256 + threadIdx.x;  // 1024*40
  int r = idx / 40;
  int c8 = idx - r * 40;
  int col0 = c8 * 8;
  const float* src = (r < 512) ? (Wf + (size_t)r * 300) : (Wb + (size_t)(r - 512) * 300);
  short8 o;
  #pragma unroll
  for (int e = 0; e < 8; ++e)
    o[e] = (col0 + e < 300) ? (short)f2bf(src[col0 + e]) : (short)0;
  *(short8*)&Wp[(size_t)r * 320 + col0] = o;
}

// ---------------- GEMM: G[65536][1024] bf16 = A[65536][320] @ Wp[1024][320]^T
__global__ __launch_bounds__(256) void gemm_kernel(const u16* __restrict__ A,
                                                   const u16* __restrict__ B,
                                                   u16* __restrict__ G) {
  __shared__ u16 At[128 * 32];
  __shared__ u16 Bt[128 * 32];
  const int tid = threadIdx.x;
  const int lane = tid & 63;
  const int wave = tid >> 6;
  const int wr = wave >> 1, wc = wave & 1;
  const int arow0 = blockIdx.x * 128;
  const int bcol0 = blockIdx.y * 128;
  floatx4 acc[4][4] = {};
  const int fq = lane >> 4;      // 0..3
  const int fr = lane & 15;      // 0..15
  for (int k0 = 0; k0 < 320; k0 += 32) {
    #pragma unroll
    for (int c = 0; c < 2; ++c) {
      int u = c * 256 + tid;         // 0..511, 16B chunk id
      int row = u >> 2;
      int cc = (u & 3) * 8;
      short8 va = *(const short8*)&A[(size_t)(arow0 + row) * 320 + k0 + cc];
      *(short8*)&At[row * 32 + cc] = va;
      short8 vb = *(const short8*)&B[(size_t)(bcol0 + row) * 320 + k0 + cc];
      *(short8*)&Bt[row * 32 + cc] = vb;
    }
    __syncthreads();
    short8 af[4], bfr[4];
    #pragma unroll
    for (int mi = 0; mi < 4; ++mi)
      af[mi] = *(const short8*)&At[(wr * 64 + mi * 16 + fr) * 32 + fq * 8];
    #pragma unroll
    for (int ni = 0; ni < 4; ++ni)
      bfr[ni] = *(const short8*)&Bt[(wc * 64 + ni * 16 + fr) * 32 + fq * 8];
    #pragma unroll
    for (int mi = 0; mi < 4; ++mi)
      #pragma unroll
      for (int ni = 0; ni < 4; ++ni)
        acc[mi][ni] = __builtin_amdgcn_mfma_f32_16x16x32_bf16(af[mi], bfr[ni], acc[mi][ni], 0, 0, 0);
    __syncthreads();
  }
  #pragma unroll
  for (int mi = 0; mi < 4; ++mi)
    #pragma unroll
    for (int ni = 0; ni < 4; ++ni)
      #pragma unroll
      for (int r = 0; r < 4; ++r) {
        int row = arow0 + wr * 64 + mi * 16 + fq * 4 + r;
        int col = bcol0 + wc * 64 + ni * 16 + fr;
        G[(size_t)row * 1024 + col] = f2bf(acc[mi][ni][r]);
      }
}

// ---------------- LSTM recurrence: 256 WGs = (dir, batch), 512 threads = gate rows
__global__ __launch_bounds__(512) void lstm_kernel(const u16* __restrict__ G,
                                                   const float* __restrict__ Whh_f,
                                                   const float* __restrict__ bias_f,
                                                   const float* __restrict__ Whh_b,
                                                   const float* __restrict__ bias_b,
                                                   float* __restrict__ hs) {
  const int wg = blockIdx.x;
  const int d = wg >> 7;
  const int b = wg & 127;
  const int j = threadIdx.x;
  const float* Whh = d ? Whh_b : Whh_f;
  const float* bias = d ? bias_b : bias_f;
  float w[128];
  #pragma unroll
  for (int k = 0; k < 128; k += 4) {
    float4 v = *(const float4*)&Whh[(size_t)j * 128 + k];
    w[k] = v.x; w[k + 1] = v.y; w[k + 2] = v.z; w[k + 3] = v.w;
  }
  const float bj = bias[j];
  __shared__ __align__(16) float hbuf[128];
  __shared__ float gbuf[512];
  float c = 0.f;
  if (j < 128) hbuf[j] = 0.f;
  __syncthreads();
  const size_t gbase = (size_t)b * 512 * 1024 + (size_t)(d << 9) + j;
  int t = d ? 511 : 0;
  const int tstep = d ? -1 : 1;
  float gnext = bf2f(G[gbase + (size_t)t * 1024]);
  for (int s = 0; s < 512; ++s) {
    float gcur = gnext;
    int tn = t + tstep;
    if (s < 511) gnext = bf2f(G[gbase + (size_t)tn * 1024]);
    float a0 = 0.f, a1 = 0.f, a2 = 0.f, a3 = 0.f;
    #pragma unroll
    for (int k = 0; k < 128; k += 16) {
      float4 h0 = *(const float4*)&hbuf[k];
      float4 h1 = *(const float4*)&hbuf[k + 4];
      float4 h2 = *(const float4*)&hbuf[k + 8];
      float4 h3 = *(const float4*)&hbuf[k + 12];
      a0 += w[k]      * h0.x + w[k + 1]  * h0.y + w[k + 2]  * h0.z + w[k + 3]  * h0.w;
      a1 += w[k + 4]  * h1.x + w[k + 5]  * h1.y + w[k + 6]  * h1.z + w[k + 7]  * h1.w;
      a2 += w[k + 8]  * h2.x + w[k + 9]  * h2.y + w[k + 10] * h2.z + w[k + 11] * h2.w;
      a3 += w[k + 12] * h3.x + w[k + 13] * h3.y + w[k + 14] * h3.z + w[k + 15] * h3.w;
    }
    float g = gcur + bj + ((a0 + a1) + (a2 + a3));
    gbuf[j] = g;
    __syncthreads();
    if (j < 128) {
      float gi = gbuf[j], gf = gbuf[j + 128], gc = gbuf[j + 256], go = gbuf[j + 384];
      c = sigm(gf) * c + sigm(gi) * tanhfast(gc);
      float h = sigm(go) * tanhfast(c);
      hbuf[j] = h;
      hs[((size_t)(b * 512 + t)) * 256 + (d << 7) + j] = h;
    }
    __syncthreads();
    t = tn;
  }
}

// ---------------- emissions: y[65536][12] = hs[65536][256] @ Wout^T + bout
__global__ __launch_bounds__(256) void emis_kernel(const float* __restrict__ hs,
                                                   const float* __restrict__ Wout,
                                                   const float* __restrict__ bout,
                                                   float* __restrict__ y) {
  __shared__ float Ws[12 * 256];
  __shared__ float bs[12];
  const int tid = threadIdx.x;
  for (int i = tid; i < 12 * 256; i += 256) Ws[i] = Wout[i];
  if (tid < 12) bs[tid] = bout[tid];
  __syncthreads();
  const int wave = tid >> 6, lane = tid & 63;
  const size_t m = (size_t)blockIdx.x * 4 + wave;
  float4 h4 = *(const float4*)&hs[m * 256 + lane * 4];
  float p[12];
  #pragma unroll
  for (int tg = 0; tg < 12; ++tg) {
    float4 wv = *(const float4*)&Ws[tg * 256 + lane * 4];
    p[tg] = h4.x * wv.x + h4.y * wv.y + h4.z * wv.z + h4.w * wv.w;
  }
  #pragma unroll
  for (int off = 32; off; off >>= 1)
    #pragma unroll
    for (int tg = 0; tg < 12; ++tg)
      p[tg] += __shfl_xor(p[tg], off);
  if (lane == 0) {
    #pragma unroll
    for (int tg = 0; tg < 12; ++tg)
      y[m * 12 + tg] = p[tg] + bs[tg];
  }
}

// ---------------- CRF: forward Z + gold score, one wave per batch
__global__ __launch_bounds__(64) void crf_kernel(const float* __restrict__ y,
                                                 const int* __restrict__ y0,
                                                 const float* __restrict__ trans,
                                                 float* __restrict__ out) {
  const int b = blockIdx.x;
  const int lane = threadIdx.x;
  __shared__ float trs[144];
  for (int i = lane; i < 144; i += 64) trs[i] = trans[i];
  __syncthreads();
  float etr[12];
  #pragma unroll
  for (int jj = 0; jj < 12; ++jj) etr[jj] = 0.f;
  float s = NEGV, treos = 0.f;
  if (lane < 12) {
    #pragma unroll
    for (int jj = 0; jj < 12; ++jj) etr[jj] = __expf(trs[lane * 12 + jj]);
    s = (lane == SOS) ? 0.f : NEGV;
    treos = trs[EOS * 12 + lane];
  }
  const float* yb = y + (size_t)b * 512 * 12;
  float e0 = (lane < 12) ? yb[lane] : 0.f;
  float e1 = (lane < 12) ? yb[12 + lane] : 0.f;
  for (int t = 0; t < 512; ++t) {
    float emit = e0;
    e0 = e1;
    if (t + 2 < 512 && lane < 12) e1 = yb[(t + 2) * 12 + lane];
    float sj[12]; float M = -INFINITY;
    #pragma unroll
    for (int jj = 0; jj < 12; ++jj) { sj[jj] = __shfl(s, jj); M = fmaxf(M, sj[jj]); }
    if (lane < 12) {
      float sum = 0.f;
      #pragma unroll
      for (int jj = 0; jj < 12; ++jj) sum += __expf(sj[jj] - M) * etr[jj];
      s = M + __logf(sum) + emit;
    }
  }
  float v = (lane < 12) ? s + treos : -INFINITY;
  float M2 = v;
  #pragma unroll
  for (int off = 32; off; off >>= 1) M2 = fmaxf(M2, __shfl_xor(M2, off));
  float e = __expf(v - M2);
  #pragma unroll
  for (int off = 32; off; off >>= 1) e += __shfl_xor(e, off);
  const float Z = M2 + __logf(e);
  const int* y0b = y0 + (size_t)b * 512;
  float acc = 0.f;
  for (int t = lane; t < 512; t += 64) {
    int cur = y0b[t];
    int prev = t ? y0b[t - 1] : SOS;
    acc += yb[t * 12 + cur] + trs[cur * 12 + prev];
  }
  #pragma unroll
  for (int off = 32; off; off >>= 1) acc += __shfl_xor(acc, off);
  if (lane == 0) {
    float gold = acc + trs[EOS * 12 + y0b[511]];
    out[b] = Z - gold;
  }
}

extern "C" void kernel_launch(void* const* d_in, const int* in_sizes, int n_in,
                              void* d_out, int out_size, void* d_ws, size_t ws_size,
                              hipStream_t stream) {
  (void)in_sizes; (void)n_in; (void)out_size; (void)ws_size;
  const int*   x     = (const int*)d_in[0];
  const int*   y0    = (const int*)d_in[1];
  const float* embed = (const float*)d_in[2];
  const float* Wih_f = (const float*)d_in[3];
  const float* Whh_f = (const float*)d_in[4];
  const float* b_f   = (const float*)d_in[5];
  const float* Wih_b = (const float*)d_in[6];
  const float* Whh_b = (const float*)d_in[7];
  const float* b_b   = (const float*)d_in[8];
  const float* Wout  = (const float*)d_in[9];
  const float* bout  = (const float*)d_in[10];
  const float* trans = (const float*)d_in[11];
  float* out = (float*)d_out;

  char* ws = (char*)d_ws;
  u16*   A  = (u16*)(ws);                      // 65536*320 bf16  = 41,943,040 B
  u16*   Wp = (u16*)(ws + 41943040);           // 1024*320  bf16  =    655,360 B
  u16*   G  = (u16*)(ws + 42598400);           // 65536*1024 bf16 = 134,217,728 B
  float* hs = (float*)(ws + 176816128);        // 65536*256 f32   =  67,108,864 B
  float* yy = (float*)(ws + 243924992);        // 65536*12  f32   =   3,145,728 B

  gather_kernel<<<10240, 256, 0, stream>>>(embed, x, A);
  wpack_kernel<<<160, 256, 0, stream>>>(Wih_f, Wih_b, Wp);
  gemm_kernel<<<dim3(512, 8), 256, 0, stream>>>(A, Wp, G);
  lstm_kernel<<<256, 512, 0, stream>>>(G, Whh_f, b_f, Whh_b, b_b, hs);
  emis_kernel<<<16384, 256, 0, stream>>>(hs, Wout, bout, yy);
  crf_kernel<<<128, 64, 0, stream>>>(yy, y0, trans, out);
}

// Round 2
// 848.287 us; speedup vs baseline: 1.2546x; 1.2546x over previous
//
#include <hip/hip_runtime.h>

typedef unsigned short u16;
typedef __attribute__((ext_vector_type(8))) short short8;
typedef __attribute__((ext_vector_type(4))) float floatx4;

#define SOS 3
#define EOS 4
#define NEGV -10000.0f

__device__ __forceinline__ float bf2f(u16 u) {
  union { unsigned int i; float f; } v; v.i = ((unsigned int)u) << 16; return v.f;
}
__device__ __forceinline__ u16 f2bf(float f) {
  union { float f; unsigned int i; } v; v.f = f;
  unsigned int r = (v.i + 0x7FFFu + ((v.i >> 16) & 1u)) >> 16;
  return (u16)r;
}

// ---------------- gather: A[65536][320] bf16 = embed[x[m]][k], zero-pad k>=300
__global__ __launch_bounds__(256) void gather_kernel(const float* __restrict__ embed,
                                                     const int* __restrict__ x,
                                                     u16* __restrict__ A) {
  int idx = blockIdx.x * 256 + threadIdx.x;   // 65536*40 chunks of 8
  int row = idx / 40;
  int c8 = idx - row * 40;
  int col0 = c8 * 8;
  const float* src = embed + (size_t)x[row] * 300 + col0;
  short8 o;
  if (col0 + 8 <= 300) {
    float4 f0 = *(const float4*)(src);
    float4 f1 = *(const float4*)(src + 4);
    o[0] = (short)f2bf(f0.x); o[1] = (short)f2bf(f0.y);
    o[2] = (short)f2bf(f0.z); o[3] = (short)f2bf(f0.w);
    o[4] = (short)f2bf(f1.x); o[5] = (short)f2bf(f1.y);
    o[6] = (short)f2bf(f1.z); o[7] = (short)f2bf(f1.w);
  } else {
    #pragma unroll
    for (int e = 0; e < 8; ++e)
      o[e] = (col0 + e < 300) ? (short)f2bf(src[e]) : (short)0;
  }
  *(short8*)&A[(size_t)row * 320 + col0] = o;
}

// ---------------- pack W: Wp[1024][320] bf16 = [Wih_f; Wih_b], zero-pad
__global__ __launch_bounds__(256) void wpack_kernel(const float* __restrict__ Wf,
                                                    const float* __restrict__ Wb,
                                                    u16* __restrict__ Wp) {
  int idx = blockIdx.x * 256 + threadIdx.x;  // 1024*40
  int r = idx / 40;
  int c8 = idx - r * 40;
  int col0 = c8 * 8;
  const float* src = (r < 512) ? (Wf + (size_t)r * 300) : (Wb + (size_t)(r - 512) * 300);
  short8 o;
  #pragma unroll
  for (int e = 0; e < 8; ++e)
    o[e] = (col0 + e < 300) ? (short)f2bf(src[col0 + e]) : (short)0;
  *(short8*)&Wp[(size_t)r * 320 + col0] = o;
}

// ---------------- GEMM: G[65536][1024] bf16 = A[65536][320] @ Wp[1024][320]^T + bias
__global__ __launch_bounds__(256) void gemm_kernel(const u16* __restrict__ A,
                                                   const u16* __restrict__ B,
                                                   const float* __restrict__ bf_,
                                                   const float* __restrict__ bb_,
                                                   u16* __restrict__ G) {
  __shared__ u16 At[128 * 32];
  __shared__ u16 Bt[128 * 32];
  const int tid = threadIdx.x;
  const int lane = tid & 63;
  const int wave = tid >> 6;
  const int wr = wave >> 1, wc = wave & 1;
  const int arow0 = blockIdx.x * 128;
  const int bcol0 = blockIdx.y * 128;
  floatx4 acc[4][4] = {};
  const int fq = lane >> 4;      // 0..3
  const int fr = lane & 15;      // 0..15
  for (int k0 = 0; k0 < 320; k0 += 32) {
    #pragma unroll
    for (int c = 0; c < 2; ++c) {
      int u = c * 256 + tid;         // 0..511, 16B chunk id
      int row = u >> 2;
      int cc = (u & 3) * 8;
      short8 va = *(const short8*)&A[(size_t)(arow0 + row) * 320 + k0 + cc];
      *(short8*)&At[row * 32 + cc] = va;
      short8 vb = *(const short8*)&B[(size_t)(bcol0 + row) * 320 + k0 + cc];
      *(short8*)&Bt[row * 32 + cc] = vb;
    }
    __syncthreads();
    short8 af[4], bfr[4];
    #pragma unroll
    for (int mi = 0; mi < 4; ++mi)
      af[mi] = *(const short8*)&At[(wr * 64 + mi * 16 + fr) * 32 + fq * 8];
    #pragma unroll
    for (int ni = 0; ni < 4; ++ni)
      bfr[ni] = *(const short8*)&Bt[(wc * 64 + ni * 16 + fr) * 32 + fq * 8];
    #pragma unroll
    for (int mi = 0; mi < 4; ++mi)
      #pragma unroll
      for (int ni = 0; ni < 4; ++ni)
        acc[mi][ni] = __builtin_amdgcn_mfma_f32_16x16x32_bf16(af[mi], bfr[ni], acc[mi][ni], 0, 0, 0);
    __syncthreads();
  }
  float biasv[4];
  #pragma unroll
  for (int ni = 0; ni < 4; ++ni) {
    int col = bcol0 + wc * 64 + ni * 16 + fr;
    biasv[ni] = (col < 512) ? bf_[col] : bb_[col - 512];
  }
  #pragma unroll
  for (int mi = 0; mi < 4; ++mi)
    #pragma unroll
    for (int ni = 0; ni < 4; ++ni)
      #pragma unroll
      for (int r = 0; r < 4; ++r) {
        int row = arow0 + wr * 64 + mi * 16 + fq * 4 + r;
        int col = bcol0 + wc * 64 + ni * 16 + fr;
        G[(size_t)row * 1024 + col] = f2bf(acc[mi][ni][r] + biasv[ni]);
      }
}

// ---------------- MFMA LSTM: 16 WGs = (dir 2) x (batch-group 8), 512 thr = 8 waves
// WG handles 16 batches of one direction. Wave w owns gate-cols {g*128 + 16w + c}.
// B-fragments (Whh) resident in VGPRs for all 512 steps. h double-buffered in LDS,
// bf16, XOR-swizzled (j ^ ((b&7)<<3)) to kill the stride-256B bank conflict.
__global__ __launch_bounds__(512) void lstm_mfma_kernel(const u16* __restrict__ G,
                                                        const float* __restrict__ Whh_f,
                                                        const float* __restrict__ Whh_b,
                                                        float* __restrict__ hs) {
  const int d  = blockIdx.x >> 3;
  const int b0 = (blockIdx.x & 7) * 16;
  const int tid = threadIdx.x;
  const int w    = tid >> 6;        // wave id 0..7 -> j in [16w, 16w+16)
  const int lane = tid & 63;
  const int c  = lane & 15;         // col-within-frag (A-row batch / C-col j)
  const int fq = lane >> 4;         // k-chunk (A) / row-group (C)
  const float* Wd = d ? Whh_b : Whh_f;

  // ---- load Whh B-fragments: Bf[gate][kk], each lane 8 bf16 = W[g*128+16w+c][fq*8+kk*32+e]
  short8 Bf[4][4];
  #pragma unroll
  for (int g = 0; g < 4; ++g)
    #pragma unroll
    for (int kk = 0; kk < 4; ++kk) {
      const float* src = Wd + (size_t)(g * 128 + 16 * w + c) * 128 + fq * 8 + kk * 32;
      float4 x0 = *(const float4*)src;
      float4 x1 = *(const float4*)(src + 4);
      short8 o;
      o[0] = (short)f2bf(x0.x); o[1] = (short)f2bf(x0.y);
      o[2] = (short)f2bf(x0.z); o[3] = (short)f2bf(x0.w);
      o[4] = (short)f2bf(x1.x); o[5] = (short)f2bf(x1.y);
      o[6] = (short)f2bf(x1.z); o[7] = (short)f2bf(x1.w);
      Bf[g][kk] = o;
    }

  __shared__ __align__(16) u16 hbuf[2][2048];    // [buf][b*128 + swz(j,b)] bf16
  for (int i = tid; i < 4096; i += 512) (&hbuf[0][0])[i] = 0;
  __syncthreads();

  float cst[4] = {0.f, 0.f, 0.f, 0.f};           // cell state, batches fq*4+r, col j
  const int jj = 16 * w + c;
  const size_t colb = (size_t)(d * 512 + jj);

  // ---- G prefetch (1 step ahead): 16 bf16 = 4 gates x 4 batches
  u16 gpre[16];
  {
    const int t0 = d ? 511 : 0;
    #pragma unroll
    for (int g = 0; g < 4; ++g)
      #pragma unroll
      for (int r = 0; r < 4; ++r)
        gpre[g * 4 + r] = G[((size_t)(b0 + fq * 4 + r) * 512 + t0) * 1024 + colb + g * 128];
  }

  int cur = 0;
  for (int s = 0; s < 512; ++s) {
    const int t = d ? 511 - s : s;
    u16 gc[16];
    #pragma unroll
    for (int i = 0; i < 16; ++i) gc[i] = gpre[i];
    if (s < 511) {
      const int tn = d ? t - 1 : t + 1;
      #pragma unroll
      for (int g = 0; g < 4; ++g)
        #pragma unroll
        for (int r = 0; r < 4; ++r)
          gpre[g * 4 + r] = G[((size_t)(b0 + fq * 4 + r) * 512 + tn) * 1024 + colb + g * 128];
    }
    // A-fragments from h_cur: lane row = batch c, k = fq*8 + kk*32 (+e)
    short8 Af[4];
    #pragma unroll
    for (int kk = 0; kk < 4; ++kk) {
      int idx = c * 128 + ((fq * 8 + kk * 32) ^ ((c & 7) << 3));
      Af[kk] = *(const short8*)&hbuf[cur][idx];
    }
    floatx4 acc[4];
    #pragma unroll
    for (int g = 0; g < 4; ++g) {
      floatx4 a;
      #pragma unroll
      for (int r = 0; r < 4; ++r) a[r] = bf2f(gc[g * 4 + r]);
      acc[g] = a;
    }
    #pragma unroll
    for (int kk = 0; kk < 4; ++kk)
      #pragma unroll
      for (int g = 0; g < 4; ++g)
        acc[g] = __builtin_amdgcn_mfma_f32_16x16x32_bf16(Af[kk], Bf[g][kk], acc[g], 0, 0, 0);
    // activations: all 4 gates of (b=fq*4+r, j=jj) live in this lane
    #pragma unroll
    for (int r = 0; r < 4; ++r) {
      float i_ = acc[0][r], f_ = acc[1][r], g_ = acc[2][r], o_ = acc[3][r];
      float p  = __expf(fminf(fmaxf(2.f * g_, -30.f), 30.f));          // e^{2g}
      float qi = __expf(-i_);
      float ig = (p - 1.f) * __builtin_amdgcn_rcpf((1.f + qi) * (p + 1.f)); // sig(i)*tanh(g)
      float qf = __expf(-f_);
      float sf = __builtin_amdgcn_rcpf(1.f + qf);                      // sig(f)
      float cn = sf * cst[r] + ig;
      cst[r] = cn;
      float qo = __expf(-o_);
      float v  = __expf(fminf(fmaxf(2.f * cn, -30.f), 30.f));          // e^{2c}
      float h  = (v - 1.f) * __builtin_amdgcn_rcpf((1.f + qo) * (v + 1.f)); // sig(o)*tanh(c)
      const int b = fq * 4 + r;
      hbuf[cur ^ 1][b * 128 + (jj ^ ((b & 7) << 3))] = f2bf(h);
      hs[((size_t)(b0 + b) * 512 + t) * 256 + d * 128 + jj] = h;
    }
    __syncthreads();
    cur ^= 1;
  }
}

// ---------------- emissions: y[65536][12] = hs[65536][256] @ Wout^T + bout
__global__ __launch_bounds__(256) void emis_kernel(const float* __restrict__ hs,
                                                   const float* __restrict__ Wout,
                                                   const float* __restrict__ bout,
                                                   float* __restrict__ y) {
  __shared__ float Ws[12 * 256];
  __shared__ float bs[12];
  const int tid = threadIdx.x;
  for (int i = tid; i < 12 * 256; i += 256) Ws[i] = Wout[i];
  if (tid < 12) bs[tid] = bout[tid];
  __syncthreads();
  const int wave = tid >> 6, lane = tid & 63;
  const size_t m = (size_t)blockIdx.x * 4 + wave;
  float4 h4 = *(const float4*)&hs[m * 256 + lane * 4];
  float p[12];
  #pragma unroll
  for (int tg = 0; tg < 12; ++tg) {
    float4 wv = *(const float4*)&Ws[tg * 256 + lane * 4];
    p[tg] = h4.x * wv.x + h4.y * wv.y + h4.z * wv.z + h4.w * wv.w;
  }
  #pragma unroll
  for (int off = 32; off; off >>= 1)
    #pragma unroll
    for (int tg = 0; tg < 12; ++tg)
      p[tg] += __shfl_xor(p[tg], off);
  if (lane == 0) {
    #pragma unroll
    for (int tg = 0; tg < 12; ++tg)
      y[m * 12 + tg] = p[tg] + bs[tg];
  }
}

// ---------------- CRF: forward Z + gold score, one wave per batch
__global__ __launch_bounds__(64) void crf_kernel(const float* __restrict__ y,
                                                 const int* __restrict__ y0,
                                                 const float* __restrict__ trans,
                                                 float* __restrict__ out) {
  const int b = blockIdx.x;
  const int lane = threadIdx.x;
  __shared__ float trs[144];
  for (int i = lane; i < 144; i += 64) trs[i] = trans[i];
  __syncthreads();
  float etr[12];
  #pragma unroll
  for (int jj = 0; jj < 12; ++jj) etr[jj] = 0.f;
  float s = NEGV, treos = 0.f;
  if (lane < 12) {
    #pragma unroll
    for (int jj = 0; jj < 12; ++jj) etr[jj] = __expf(trs[lane * 12 + jj]);
    s = (lane == SOS) ? 0.f : NEGV;
    treos = trs[EOS * 12 + lane];
  }
  const float* yb = y + (size_t)b * 512 * 12;
  float e0 = (lane < 12) ? yb[lane] : 0.f;
  float e1 = (lane < 12) ? yb[12 + lane] : 0.f;
  for (int t = 0; t < 512; ++t) {
    float emit = e0;
    e0 = e1;
    if (t + 2 < 512 && lane < 12) e1 = yb[(t + 2) * 12 + lane];
    float sj[12]; float M = -INFINITY;
    #pragma unroll
    for (int jj = 0; jj < 12; ++jj) { sj[jj] = __shfl(s, jj); M = fmaxf(M, sj[jj]); }
    if (lane < 12) {
      float sum = 0.f;
      #pragma unroll
      for (int jj = 0; jj < 12; ++jj) sum += __expf(sj[jj] - M) * etr[jj];
      s = M + __logf(sum) + emit;
    }
  }
  float v = (lane < 12) ? s + treos : -INFINITY;
  float M2 = v;
  #pragma unroll
  for (int off = 32; off; off >>= 1) M2 = fmaxf(M2, __shfl_xor(M2, off));
  float e = __expf(v - M2);
  #pragma unroll
  for (int off = 32; off; off >>= 1) e += __shfl_xor(e, off);
  const float Z = M2 + __logf(e);
  const int* y0b = y0 + (size_t)b * 512;
  float acc = 0.f;
  for (int t = lane; t < 512; t += 64) {
    int cur = y0b[t];
    int prev = t ? y0b[t - 1] : SOS;
    acc += yb[t * 12 + cur] + trs[cur * 12 + prev];
  }
  #pragma unroll
  for (int off = 32; off; off >>= 1) acc += __shfl_xor(acc, off);
  if (lane == 0) {
    float gold = acc + trs[EOS * 12 + y0b[511]];
    out[b] = Z - gold;
  }
}

extern "C" void kernel_launch(void* const* d_in, const int* in_sizes, int n_in,
                              void* d_out, int out_size, void* d_ws, size_t ws_size,
                              hipStream_t stream) {
  (void)in_sizes; (void)n_in; (void)out_size; (void)ws_size;
  const int*   x     = (const int*)d_in[0];
  const int*   y0    = (const int*)d_in[1];
  const float* embed = (const float*)d_in[2];
  const float* Wih_f = (const float*)d_in[3];
  const float* Whh_f = (const float*)d_in[4];
  const float* b_f   = (const float*)d_in[5];
  const float* Wih_b = (const float*)d_in[6];
  const float* Whh_b = (const float*)d_in[7];
  const float* b_b   = (const float*)d_in[8];
  const float* Wout  = (const float*)d_in[9];
  const float* bout  = (const float*)d_in[10];
  const float* trans = (const float*)d_in[11];
  float* out = (float*)d_out;

  char* ws = (char*)d_ws;
  u16*   A  = (u16*)(ws);                      // 65536*320 bf16  = 41,943,040 B
  u16*   Wp = (u16*)(ws + 41943040);           // 1024*320  bf16  =    655,360 B
  u16*   G  = (u16*)(ws + 42598400);           // 65536*1024 bf16 = 134,217,728 B
  float* hs = (float*)(ws + 176816128);        // 65536*256 f32   =  67,108,864 B
  float* yy = (float*)(ws + 243924992);        // 65536*12  f32   =   3,145,728 B

  gather_kernel<<<10240, 256, 0, stream>>>(embed, x, A);
  wpack_kernel<<<160, 256, 0, stream>>>(Wih_f, Wih_b, Wp);
  gemm_kernel<<<dim3(512, 8), 256, 0, stream>>>(A, Wp, b_f, b_b, G);
  lstm_mfma_kernel<<<16, 512, 0, stream>>>(G, Whh_f, Whh_b, hs);
  emis_kernel<<<16384, 256, 0, stream>>>(hs, Wout, bout, yy);
  crf_kernel<<<128, 64, 0, stream>>>(yy, y0, trans, out);
}

// Round 3
// 836.061 us; speedup vs baseline: 1.2729x; 1.0146x over previous
//
#include <hip/hip_runtime.h>

typedef unsigned short u16;
typedef __attribute__((ext_vector_type(8))) short short8;
typedef __attribute__((ext_vector_type(4))) float floatx4;

#define SOS 3
#define EOS 4
#define NEGV -10000.0f
#define LOG2E 1.442695041f
#define TWOLOG2E 2.885390082f

__device__ __forceinline__ float bf2f(u16 u) {
  union { unsigned int i; float f; } v; v.i = ((unsigned int)u) << 16; return v.f;
}
__device__ __forceinline__ u16 f2bf(float f) {
  union { float f; unsigned int i; } v; v.f = f;
  unsigned int r = (v.i + 0x7FFFu + ((v.i >> 16) & 1u)) >> 16;
  return (u16)r;
}
__device__ __forceinline__ void gload_lds16(const u16* g, u16* l) {
  __builtin_amdgcn_global_load_lds((const __attribute__((address_space(1))) void*)g,
                                   (__attribute__((address_space(3))) void*)l, 16, 0, 0);
}

// ---------------- gather: A[m=t*128+b][320] bf16 = embed[x[b][t]][k], zero-pad k>=300
__global__ __launch_bounds__(256) void gather_kernel(const float* __restrict__ embed,
                                                     const int* __restrict__ x,
                                                     u16* __restrict__ A) {
  int idx = blockIdx.x * 256 + threadIdx.x;   // 65536*40 chunks of 8
  int row = idx / 40;                          // m = t*128 + b
  int c8 = idx - row * 40;
  int col0 = c8 * 8;
  int b = row & 127, t = row >> 7;
  const float* src = embed + (size_t)x[b * 512 + t] * 300 + col0;
  short8 o;
  if (col0 + 8 <= 300) {
    float4 f0 = *(const float4*)(src);
    float4 f1 = *(const float4*)(src + 4);
    o[0] = (short)f2bf(f0.x); o[1] = (short)f2bf(f0.y);
    o[2] = (short)f2bf(f0.z); o[3] = (short)f2bf(f0.w);
    o[4] = (short)f2bf(f1.x); o[5] = (short)f2bf(f1.y);
    o[6] = (short)f2bf(f1.z); o[7] = (short)f2bf(f1.w);
  } else {
    #pragma unroll
    for (int e = 0; e < 8; ++e)
      o[e] = (col0 + e < 300) ? (short)f2bf(src[e]) : (short)0;
  }
  *(short8*)&A[(size_t)row * 320 + col0] = o;
}

// ---------------- pack W: Wp[1024][320] bf16 = [Wih_f; Wih_b], zero-pad
__global__ __launch_bounds__(256) void wpack_kernel(const float* __restrict__ Wf,
                                                    const float* __restrict__ Wb,
                                                    u16* __restrict__ Wp) {
  int idx = blockIdx.x * 256 + threadIdx.x;  // 1024*40
  int r = idx / 40;
  int c8 = idx - r * 40;
  int col0 = c8 * 8;
  const float* src = (r < 512) ? (Wf + (size_t)r * 300) : (Wb + (size_t)(r - 512) * 300);
  short8 o;
  #pragma unroll
  for (int e = 0; e < 8; ++e)
    o[e] = (col0 + e < 300) ? (short)f2bf(src[col0 + e]) : (short)0;
  *(short8*)&Wp[(size_t)r * 320 + col0] = o;
}

// ---------------- GEMM: G[65536][1024] bf16 = A @ Wp^T + bias, m97-style staging
__global__ __launch_bounds__(256) void gemm_kernel(const u16* __restrict__ A,
                                                   const u16* __restrict__ B,
                                                   const float* __restrict__ bf_,
                                                   const float* __restrict__ bb_,
                                                   u16* __restrict__ G) {
  __shared__ u16 At[128 * 32];
  __shared__ u16 Bt[128 * 32];
  // XCD-chunked remap: XCD k (= n%8) gets bx in [k*64, k*64+64), its 8 by-blocks
  // consecutive -> A-panel fetched once per XCD, B tiny and fully L2-resident.
  const int n = blockIdx.x;
  const int xcd = n & 7, rr = n >> 3;
  const int bx = xcd * 64 + (rr >> 3);
  const int by = rr & 7;
  const int tid = threadIdx.x;
  const int lane = tid & 63;
  const int wave = tid >> 6;
  const int wr = wave >> 1, wc = wave & 1;
  const int arow0 = bx * 128;
  const int bcol0 = by * 128;
  floatx4 acc[4][4] = {};
  const int fq = lane >> 4;      // 0..3
  const int fr = lane & 15;      // 0..15
  const int sr = wave * 32 + (lane >> 2);   // staging row (q adds 16)
  const int sc = (lane & 3) * 8;            // staging col (u16)
  for (int k0 = 0; k0 < 320; k0 += 32) {
    #pragma unroll
    for (int q = 0; q < 2; ++q) {
      gload_lds16(&A[(size_t)(arow0 + sr + q * 16) * 320 + k0 + sc], &At[wave * 1024 + q * 512]);
      gload_lds16(&B[(size_t)(bcol0 + sr + q * 16) * 320 + k0 + sc], &Bt[wave * 1024 + q * 512]);
    }
    __syncthreads();
    short8 af[4], bfr[4];
    #pragma unroll
    for (int mi = 0; mi < 4; ++mi)
      af[mi] = *(const short8*)&At[(wr * 64 + mi * 16 + fr) * 32 + fq * 8];
    #pragma unroll
    for (int ni = 0; ni < 4; ++ni)
      bfr[ni] = *(const short8*)&Bt[(wc * 64 + ni * 16 + fr) * 32 + fq * 8];
    #pragma unroll
    for (int mi = 0; mi < 4; ++mi)
      #pragma unroll
      for (int ni = 0; ni < 4; ++ni)
        acc[mi][ni] = __builtin_amdgcn_mfma_f32_16x16x32_bf16(af[mi], bfr[ni], acc[mi][ni], 0, 0, 0);
    __syncthreads();
  }
  float biasv[4];
  #pragma unroll
  for (int ni = 0; ni < 4; ++ni) {
    int col = bcol0 + wc * 64 + ni * 16 + fr;
    biasv[ni] = (col < 512) ? bf_[col] : bb_[col - 512];
  }
  #pragma unroll
  for (int mi = 0; mi < 4; ++mi)
    #pragma unroll
    for (int ni = 0; ni < 4; ++ni)
      #pragma unroll
      for (int r = 0; r < 4; ++r) {
        int row = arow0 + wr * 64 + mi * 16 + fq * 4 + r;
        int col = bcol0 + wc * 64 + ni * 16 + fr;
        G[(size_t)row * 1024 + col] = f2bf(acc[mi][ni][r] + biasv[ni]);
      }
}

// ---------------- MFMA LSTM, swapped operands: D[j][b] = Whh @ h^T
// 16 WGs = (dir 2) x (batch-group 8 of 16). Wave w owns j-tile [16w,16w+16) per gate.
// Lane (fq,fr): A-frag row fr (j=g*128+16w+fr), B-frag col fr (batch), D: j=16w+fq*4+i, b=fr.
// G layout rows m=t*128+b -> lane's 16 G values = 4x dwordx2. Raw s_barrier (no vmcnt
// drain) + depth-3 register prefetch => automatic counted vmcnt. LDS stride 136.
__global__ __launch_bounds__(512) void lstm_mfma_kernel(const u16* __restrict__ Gp,
                                                        const float* __restrict__ Whh_f,
                                                        const float* __restrict__ Whh_b,
                                                        u16* __restrict__ hs) {
  const int d  = blockIdx.x >> 3;
  const int b0 = (blockIdx.x & 7) * 16;
  const int tid = threadIdx.x;
  const int w    = tid >> 6;
  const int lane = tid & 63;
  const int fr = lane & 15;
  const int fq = lane >> 4;
  const float* Wd = d ? Whh_b : Whh_f;

  // A-operand fragments of Whh, resident all 512 steps: Wf[g][kk]
  short8 Wf[4][4];
  #pragma unroll
  for (int g = 0; g < 4; ++g)
    #pragma unroll
    for (int kk = 0; kk < 4; ++kk) {
      const float* src = Wd + (size_t)(g * 128 + 16 * w + fr) * 128 + fq * 8 + kk * 32;
      float4 x0 = *(const float4*)src;
      float4 x1 = *(const float4*)(src + 4);
      short8 o;
      o[0] = (short)f2bf(x0.x); o[1] = (short)f2bf(x0.y);
      o[2] = (short)f2bf(x0.z); o[3] = (short)f2bf(x0.w);
      o[4] = (short)f2bf(x1.x); o[5] = (short)f2bf(x1.y);
      o[6] = (short)f2bf(x1.z); o[7] = (short)f2bf(x1.w);
      Wf[g][kk] = o;
    }

  __shared__ __align__(16) u16 hbuf[2][16 * 136];   // stride 136: 272B rows, bank-rotate 4
  {
    u16* hz = &hbuf[0][0];
    for (int i = tid; i < 2 * 16 * 136; i += 512) hz[i] = 0;
  }
  __syncthreads();

  float cst[4] = {0.f, 0.f, 0.f, 0.f};
  const int ts = d ? -1 : 1;
  const int t0 = d ? 511 : 0;
  const int laneoff = (b0 + fr) * 1024 + d * 512 + 16 * w + fq * 4;  // G col/row lane part
  const int hoff_r = fr * 136 + fq * 8;                              // B-frag read base
  const int hoff_w = fr * 136 + 16 * w + fq * 4;                     // h write addr
  u16* hsbase = hs + (size_t)(b0 + fr) * 512 * 256 + d * 128 + 16 * w + fq * 4;

  uint2 gA[4], gB[4], gC[4];
#define LOADG(GB_, TP_) { \
    const u16* p_ = Gp + (long long)(TP_) * 131072 + laneoff; \
    _Pragma("unroll") \
    for (int g_ = 0; g_ < 4; ++g_) (GB_)[g_] = *(const uint2*)(p_ + g_ * 128); \
  }
  LOADG(gA, t0); LOADG(gB, t0 + ts); LOADG(gC, t0 + 2 * ts);

  u16* hr = &hbuf[0][0];
  u16* hw = &hbuf[1][0];

  auto STEP = [&](uint2* GB, int S, bool ISSUE) {
    const int t = d ? (511 - S) : S;
    // B-operand h fragments (ds_read_b128 x4)
    short8 hf0 = *(const short8*)(hr + hoff_r);
    short8 hf1 = *(const short8*)(hr + hoff_r + 32);
    short8 hf2 = *(const short8*)(hr + hoff_r + 64);
    short8 hf3 = *(const short8*)(hr + hoff_r + 96);
    // acc init = G (prefetched 3 steps ago): bf16 pair unpack is 1 VALU each
    floatx4 acc[4];
    #pragma unroll
    for (int g = 0; g < 4; ++g) {
      floatx4 a;
      a[0] = __builtin_bit_cast(float, GB[g].x << 16);
      a[1] = __builtin_bit_cast(float, GB[g].x & 0xffff0000u);
      a[2] = __builtin_bit_cast(float, GB[g].y << 16);
      a[3] = __builtin_bit_cast(float, GB[g].y & 0xffff0000u);
      acc[g] = a;
    }
    acc[0] = __builtin_amdgcn_mfma_f32_16x16x32_bf16(Wf[0][0], hf0, acc[0], 0, 0, 0);
    acc[1] = __builtin_amdgcn_mfma_f32_16x16x32_bf16(Wf[1][0], hf0, acc[1], 0, 0, 0);
    acc[2] = __builtin_amdgcn_mfma_f32_16x16x32_bf16(Wf[2][0], hf0, acc[2], 0, 0, 0);
    acc[3] = __builtin_amdgcn_mfma_f32_16x16x32_bf16(Wf[3][0], hf0, acc[3], 0, 0, 0);
    acc[0] = __builtin_amdgcn_mfma_f32_16x16x32_bf16(Wf[0][1], hf1, acc[0], 0, 0, 0);
    acc[1] = __builtin_amdgcn_mfma_f32_16x16x32_bf16(Wf[1][1], hf1, acc[1], 0, 0, 0);
    acc[2] = __builtin_amdgcn_mfma_f32_16x16x32_bf16(Wf[2][1], hf1, acc[2], 0, 0, 0);
    acc[3] = __builtin_amdgcn_mfma_f32_16x16x32_bf16(Wf[3][1], hf1, acc[3], 0, 0, 0);
    acc[0] = __builtin_amdgcn_mfma_f32_16x16x32_bf16(Wf[0][2], hf2, acc[0], 0, 0, 0);
    acc[1] = __builtin_amdgcn_mfma_f32_16x16x32_bf16(Wf[1][2], hf2, acc[1], 0, 0, 0);
    acc[2] = __builtin_amdgcn_mfma_f32_16x16x32_bf16(Wf[2][2], hf2, acc[2], 0, 0, 0);
    acc[3] = __builtin_amdgcn_mfma_f32_16x16x32_bf16(Wf[3][2], hf2, acc[3], 0, 0, 0);
    acc[0] = __builtin_amdgcn_mfma_f32_16x16x32_bf16(Wf[0][3], hf3, acc[0], 0, 0, 0);
    acc[1] = __builtin_amdgcn_mfma_f32_16x16x32_bf16(Wf[1][3], hf3, acc[1], 0, 0, 0);
    acc[2] = __builtin_amdgcn_mfma_f32_16x16x32_bf16(Wf[2][3], hf3, acc[2], 0, 0, 0);
    acc[3] = __builtin_amdgcn_mfma_f32_16x16x32_bf16(Wf[3][3], hf3, acc[3], 0, 0, 0);
    // prefetch G for step S+3 (overwrites GB after consumption; reads past the
    // ends of G land in adjacent ws regions -> in-bounds garbage, never consumed)
    if (ISSUE) { LOADG(GB, t + 3 * ts); }
    // activations: lane owns all 4 gates of (b=b0+fr, j=16w+fq*4+i)
    float hv[4];
    #pragma unroll
    for (int i = 0; i < 4; ++i) {
      float i_ = acc[0][i], f_ = acc[1][i], g_ = acc[2][i], o_ = acc[3][i];
      float pa = fminf(fmaxf(g_ * TWOLOG2E, -100.f), 100.f);
      float p  = __builtin_amdgcn_exp2f(pa);                          // e^{2g}
      float qi = __builtin_amdgcn_exp2f(i_ * -LOG2E);                 // e^{-i}
      float ig = (p - 1.f) * __builtin_amdgcn_rcpf((1.f + qi) * (p + 1.f));
      float qf = __builtin_amdgcn_exp2f(f_ * -LOG2E);                 // e^{-f}
      float cn = __builtin_amdgcn_rcpf(1.f + qf) * cst[i] + ig;
      cst[i] = cn;
      float qo = __builtin_amdgcn_exp2f(o_ * -LOG2E);                 // e^{-o}
      float va = fminf(fmaxf(cn * TWOLOG2E, -100.f), 100.f);
      float v  = __builtin_amdgcn_exp2f(va);                          // e^{2c}
      hv[i] = (v - 1.f) * __builtin_amdgcn_rcpf((1.f + qo) * (v + 1.f));
    }
    // pack 4 h -> 2 dwords (round-to-nearest, h in (-1,1) so no overflow/NaN)
    unsigned a0 = __builtin_bit_cast(unsigned, hv[0]) + 0x8000u;
    unsigned a1 = __builtin_bit_cast(unsigned, hv[1]) + 0x8000u;
    unsigned a2 = __builtin_bit_cast(unsigned, hv[2]) + 0x8000u;
    unsigned a3 = __builtin_bit_cast(unsigned, hv[3]) + 0x8000u;
    uint2 pk;
    pk.x = (a0 >> 16) | (a1 & 0xffff0000u);
    pk.y = (a2 >> 16) | (a3 & 0xffff0000u);
    *(uint2*)(hw + hoff_w) = pk;                       // ds_write_b64
    *(uint2*)(hsbase + (size_t)t * 256) = pk;          // global dwordx2, no drain
    // sync: only LDS must be visible; vmcnt NOT drained (prefetch stays in flight)
    __builtin_amdgcn_sched_barrier(0);
    asm volatile("s_waitcnt lgkmcnt(0)");
    __builtin_amdgcn_sched_barrier(0);
    __builtin_amdgcn_s_barrier();
    __builtin_amdgcn_sched_barrier(0);
    u16* tmp = hr; hr = hw; hw = tmp;
  };

  #pragma unroll 1
  for (int s = 0; s < 510; s += 3) {
    STEP(gA, s, true);
    STEP(gB, s + 1, true);
    STEP(gC, s + 2, true);
  }
  STEP(gA, 510, false);
  STEP(gB, 511, false);
#undef LOADG
}

// ---------------- emissions: y[65536][12] = hs(bf16)[65536][256] @ Wout^T + bout
__global__ __launch_bounds__(256) void emis_kernel(const u16* __restrict__ hs,
                                                   const float* __restrict__ Wout,
                                                   const float* __restrict__ bout,
                                                   float* __restrict__ y) {
  __shared__ float Ws[12 * 256];
  __shared__ float bs[12];
  const int tid = threadIdx.x;
  for (int i = tid; i < 12 * 256; i += 256) Ws[i] = Wout[i];
  if (tid < 12) bs[tid] = bout[tid];
  __syncthreads();
  const int wave = tid >> 6, lane = tid & 63;
  const size_t m = (size_t)blockIdx.x * 4 + wave;
  uint2 hv = *(const uint2*)&hs[m * 256 + lane * 4];
  float h0 = __builtin_bit_cast(float, hv.x << 16);
  float h1 = __builtin_bit_cast(float, hv.x & 0xffff0000u);
  float h2 = __builtin_bit_cast(float, hv.y << 16);
  float h3 = __builtin_bit_cast(float, hv.y & 0xffff0000u);
  float p[12];
  #pragma unroll
  for (int tg = 0; tg < 12; ++tg) {
    const float* wv = &Ws[tg * 256 + lane * 4];
    p[tg] = h0 * wv[0] + h1 * wv[1] + h2 * wv[2] + h3 * wv[3];
  }
  #pragma unroll
  for (int off = 32; off; off >>= 1)
    #pragma unroll
    for (int tg = 0; tg < 12; ++tg)
      p[tg] += __shfl_xor(p[tg], off);
  if (lane == 0) {
    #pragma unroll
    for (int tg = 0; tg < 12; ++tg)
      y[m * 12 + tg] = p[tg] + bs[tg];
  }
}

// ---------------- CRF: forward Z + gold score, one wave per batch
__global__ __launch_bounds__(64) void crf_kernel(const float* __restrict__ y,
                                                 const int* __restrict__ y0,
                                                 const float* __restrict__ trans,
                                                 float* __restrict__ out) {
  const int b = blockIdx.x;
  const int lane = threadIdx.x;
  __shared__ float trs[144];
  for (int i = lane; i < 144; i += 64) trs[i] = trans[i];
  __syncthreads();
  float etr[12];
  #pragma unroll
  for (int jj = 0; jj < 12; ++jj) etr[jj] = 0.f;
  float s = NEGV, treos = 0.f;
  if (lane < 12) {
    #pragma unroll
    for (int jj = 0; jj < 12; ++jj) etr[jj] = __expf(trs[lane * 12 + jj]);
    s = (lane == SOS) ? 0.f : NEGV;
    treos = trs[EOS * 12 + lane];
  }
  const float* yb = y + (size_t)b * 512 * 12;
  float e0 = (lane < 12) ? yb[lane] : 0.f;
  float e1 = (lane < 12) ? yb[12 + lane] : 0.f;
  for (int t = 0; t < 512; ++t) {
    float emit = e0;
    e0 = e1;
    if (t + 2 < 512 && lane < 12) e1 = yb[(t + 2) * 12 + lane];
    float sj[12]; float M = -INFINITY;
    #pragma unroll
    for (int jj = 0; jj < 12; ++jj) { sj[jj] = __shfl(s, jj); M = fmaxf(M, sj[jj]); }
    if (lane < 12) {
      float sum = 0.f;
      #pragma unroll
      for (int jj = 0; jj < 12; ++jj) sum += __expf(sj[jj] - M) * etr[jj];
      s = M + __logf(sum) + emit;
    }
  }
  float v = (lane < 12) ? s + treos : -INFINITY;
  float M2 = v;
  #pragma unroll
  for (int off = 32; off; off >>= 1) M2 = fmaxf(M2, __shfl_xor(M2, off));
  float e = __expf(v - M2);
  #pragma unroll
  for (int off = 32; off; off >>= 1) e += __shfl_xor(e, off);
  const float Z = M2 + __logf(e);
  const int* y0b = y0 + (size_t)b * 512;
  float acc = 0.f;
  for (int t = lane; t < 512; t += 64) {
    int cur = y0b[t];
    int prev = t ? y0b[t - 1] : SOS;
    acc += yb[t * 12 + cur] + trs[cur * 12 + prev];
  }
  #pragma unroll
  for (int off = 32; off; off >>= 1) acc += __shfl_xor(acc, off);
  if (lane == 0) {
    float gold = acc + trs[EOS * 12 + y0b[511]];
    out[b] = Z - gold;
  }
}

extern "C" void kernel_launch(void* const* d_in, const int* in_sizes, int n_in,
                              void* d_out, int out_size, void* d_ws, size_t ws_size,
                              hipStream_t stream) {
  (void)in_sizes; (void)n_in; (void)out_size; (void)ws_size;
  const int*   x     = (const int*)d_in[0];
  const int*   y0    = (const int*)d_in[1];
  const float* embed = (const float*)d_in[2];
  const float* Wih_f = (const float*)d_in[3];
  const float* Whh_f = (const float*)d_in[4];
  const float* b_f   = (const float*)d_in[5];
  const float* Wih_b = (const float*)d_in[6];
  const float* Whh_b = (const float*)d_in[7];
  const float* b_b   = (const float*)d_in[8];
  const float* Wout  = (const float*)d_in[9];
  const float* bout  = (const float*)d_in[10];
  const float* trans = (const float*)d_in[11];
  float* out = (float*)d_out;

  char* ws = (char*)d_ws;
  u16*   A  = (u16*)(ws);                      // 65536*320 bf16  = 41,943,040 B
  u16*   Wp = (u16*)(ws + 41943040);           // 1024*320  bf16  =    655,360 B
  u16*   G  = (u16*)(ws + 42598400);           // 65536*1024 bf16 = 134,217,728 B
  u16*   hs = (u16*)(ws + 176816128);          // 65536*256 bf16  =  33,554,432 B
  float* yy = (float*)(ws + 210370560);        // 65536*12  f32   =   3,145,728 B

  gather_kernel<<<10240, 256, 0, stream>>>(embed, x, A);
  wpack_kernel<<<160, 256, 0, stream>>>(Wih_f, Wih_b, Wp);
  gemm_kernel<<<4096, 256, 0, stream>>>(A, Wp, b_f, b_b, G);
  lstm_mfma_kernel<<<16, 512, 0, stream>>>(G, Whh_f, Whh_b, hs);
  emis_kernel<<<16384, 256, 0, stream>>>(hs, Wout, bout, yy);
  crf_kernel<<<128, 64, 0, stream>>>(yy, y0, trans, out);
}